// Round 15
// baseline (241.998 us; speedup 1.0000x reference)
//
#include <hip/hip_runtime.h>
#include <hip/hip_bf16.h>

#define LRELU_ALPHA 0.3f
#define LN_EPS 1e-3f

typedef short bf16x8 __attribute__((ext_vector_type(8)));
typedef float f32x4 __attribute__((ext_vector_type(4)));

static __device__ __forceinline__ unsigned short f2bf(float f) {
    union { float f; unsigned u; } v; v.f = f;
    unsigned r = v.u + 0x7fffu + ((v.u >> 16) & 1u);  // RNE
    return (unsigned short)(r >> 16);
}

// async 16B global -> LDS (DMA). LDS dest = wave-uniform base + lane*16.
#define ASYNC_CP16(gsrc, ldst)                                                  \
    __builtin_amdgcn_global_load_lds(                                           \
        (const __attribute__((address_space(1))) unsigned int*)(gsrc),          \
        (__attribute__((address_space(3))) unsigned int*)(ldst), 16, 0, 0)

#define NE 1152   // extended B-rows: 1024 hidden + 15 fused-skinny + pad

// ---------------------------------------------------------------------------
// Fused prep kernel (r12): cast x, transpose big weights, weight-combine
// skinny into B rows 1024..1038, extended biases.
// ---------------------------------------------------------------------------
__global__ void prep_kernel(const float* __restrict__ x,
                            const float* __restrict__ w0a, const float* __restrict__ b0a,
                            const float* __restrict__ w0b, const float* __restrict__ b0b,
                            const float* __restrict__ w1a, const float* __restrict__ b1a,
                            const float* __restrict__ w1b, const float* __restrict__ b1b,
                            unsigned short* __restrict__ x_bf,
                            unsigned short* __restrict__ bT0, unsigned short* __restrict__ bT1,
                            float* __restrict__ be0, float* __restrict__ be1) {
    __shared__ float tile[32][33];
    const int b = blockIdx.x, tid = threadIdx.x;

    if (b < 2048) {                       // ---- cast x ----
        const int i = (b * 256 + tid) * 4;
        const float4 v = *(const float4*)(x + i);
        ushort4 o;
        o.x = f2bf(v.x); o.y = f2bf(v.y); o.z = f2bf(v.z); o.w = f2bf(v.w);
        *(ushort4*)(x_bf + i) = o;
        return;
    }
    if (b < 2560) {                       // ---- transpose w0a -> bT0 ----
        const int b2 = b - 2048;
        const int nb = (b2 & 31) * 32, kb = (b2 >> 5) * 32;
        const int tx = tid & 31, ty = tid >> 5;       // 32 x 8
#pragma unroll
        for (int i = 0; i < 4; ++i)
            tile[ty + i * 8][tx] = w0a[(size_t)(kb + ty + i * 8) * 1024 + nb + tx];
        __syncthreads();
#pragma unroll
        for (int i = 0; i < 4; ++i)
            bT0[(size_t)(nb + ty + i * 8) * 512 + kb + tx] = f2bf(tile[tx][ty + i * 8]);
        return;
    }
    if (b < 3616) {                       // ---- transpose w1a -> bT1 ----
        const int b3 = b - 2560;
        const int nb = (b3 & 31) * 32, kb = (b3 >> 5) * 32;   // kb up to 1055
        const int tx = tid & 31, ty = tid >> 5;
#pragma unroll
        for (int i = 0; i < 4; ++i) {
            const int k = kb + ty + i * 8;
            tile[ty + i * 8][tx] = (k < 1029) ? w1a[(size_t)k * 1024 + nb + tx] : 0.f;
        }
        __syncthreads();
#pragma unroll
        for (int i = 0; i < 4; ++i)
            bT1[(size_t)(nb + ty + i * 8) * 1056 + kb + tx] = f2bf(tile[tx][ty + i * 8]);
        return;
    }
    if (b < 4003) {                       // ---- wcomb 0/1 ----
        const int is1 = (b >= 3745);
        const int b4 = b - (is1 ? 3745 : 3616);
        const int w = tid >> 6, lane = tid & 63;
        const int row = b4 * 4 + w;
        const int F = is1 ? 1029 : 512;
        if (row > F) return;
        const float* wa = is1 ? w1a : w0a;
        const float* ba = is1 ? b1a : b0a;
        const float* wb = is1 ? w1b : w0b;
        const float* bb = is1 ? b1b : b0b;
        const float* src = (row < F) ? (wa + (size_t)row * 1024) : ba;
        float acc[15] = {};
        for (int h = lane; h < 1024; h += 64) {
            const float a = src[h];
            const float* wr = wb + h * 15;
#pragma unroll
            for (int c = 0; c < 15; ++c) acc[c] += a * wr[c];
        }
#pragma unroll
        for (int c = 0; c < 15; ++c)
#pragma unroll
            for (int off = 32; off > 0; off >>= 1) acc[c] += __shfl_xor(acc[c], off, 64);
        if (lane < 15) {
            if (row < F) {
                if (is1) bT1[(size_t)(1024 + lane) * 1056 + row] = f2bf(acc[lane]);
                else     bT0[(size_t)(1024 + lane) * 512  + row] = f2bf(acc[lane]);
            } else {
                if (is1) be1[1024 + lane] = acc[lane] + bb[lane];
                else     be0[1024 + lane] = acc[lane] + bb[lane];
            }
        }
        return;
    }
    {                                     // ---- bias copies ----
        const int b6 = b - 4003;
        if (b6 < 4) be0[b6 * 256 + tid] = b0a[b6 * 256 + tid];
        else        be1[(b6 - 4) * 256 + tid] = b1a[(b6 - 4) * 256 + tid];
    }
}

// ---------------------------------------------------------------------------
// bf16 MFMA GEMM: [h | t] = A[M,lda]bf16 @ (BT[NE,ldb]bf16)^T + be
// 64x64 tile, grid (18,64)=1152 = 4.5 blocks/CU. B-ONLY LDS (double-buffered,
// 8 KB): the MFMA A-fragment is a per-lane contiguous 16B global load
// (row wr+16i+m16, k=q*8..+8), so A streams global->register directly —
// removes 2 DMA + 2 ds_read_b128 per iter (halves LDS pipe traffic) and the
// A staging dependency. A next-iter fragments software-pipelined (an0/an1)
// so their L2 latency hides under ds_read+MFMA. Numerics identical to r14.
// Epilogue: cols<1024 -> h (ld 1024); 1024..1038 -> compact t (ld 15).
// ---------------------------------------------------------------------------
__global__ __launch_bounds__(256)
void mfma_gemm(const unsigned short* __restrict__ A, int lda,
               const unsigned short* __restrict__ BT, int ldb,
               const float* __restrict__ bias, float* __restrict__ C,
               float* __restrict__ t, int K) {
    __shared__ unsigned short Bs[2][64 * 32];    // 2 x 4 KB
    const int tid = threadIdx.x;
    const int w = tid >> 6, lane = tid & 63;
    const int q = lane >> 4, m16 = lane & 15;
    const int wr = (w >> 1) * 32, wc = (w & 1) * 32;
    const int br = blockIdx.y * 64, bc = blockIdx.x * 64;

    const int sr = tid >> 2;          // B staging row 0..63
    const int sc = (tid & 3) * 8;     // B staging col (elements)
    const unsigned short* gB = BT + (size_t)(bc + sr) * ldb + sc;

    // per-lane A fragment pointers: row br+wr+m16 (+16 for frag 1), col q*8
    const unsigned short* gA0 = A + (size_t)(br + wr + m16) * lda + q * 8;
    const unsigned short* gA1 = gA0 + (size_t)16 * lda;

    // prologue: prefetch B k0=0 into buffer 0; A frags k0=0 into registers
    ASYNC_CP16(gB, &Bs[0][tid * 8]);
    bf16x8 af0 = *(const bf16x8*)(gA0);
    bf16x8 af1 = *(const bf16x8*)(gA1);

    f32x4 acc[2][2] = {};
    int cur = 0;

    for (int k0 = 0; k0 < K; k0 += 32) {
        __syncthreads();              // drains B DMA into Bs[cur]
        const int nk = k0 + 32;
        bf16x8 an0 = af0, an1 = af1;
        if (nk < K) {                 // prefetch next B tile + next A frags
            ASYNC_CP16(gB + nk, &Bs[cur ^ 1][tid * 8]);
            an0 = *(const bf16x8*)(gA0 + nk);
            an1 = *(const bf16x8*)(gA1 + nk);
        }
        const bf16x8 b0 = *(const bf16x8*)(&Bs[cur][(wc + m16) * 32 + q * 8]);
        const bf16x8 b1 = *(const bf16x8*)(&Bs[cur][(wc + 16 + m16) * 32 + q * 8]);
        acc[0][0] = __builtin_amdgcn_mfma_f32_16x16x32_bf16(af0, b0, acc[0][0], 0, 0, 0);
        acc[0][1] = __builtin_amdgcn_mfma_f32_16x16x32_bf16(af0, b1, acc[0][1], 0, 0, 0);
        acc[1][0] = __builtin_amdgcn_mfma_f32_16x16x32_bf16(af1, b0, acc[1][0], 0, 0, 0);
        acc[1][1] = __builtin_amdgcn_mfma_f32_16x16x32_bf16(af1, b1, acc[1][1], 0, 0, 0);
        af0 = an0; af1 = an1;
        cur ^= 1;
    }

#pragma unroll
    for (int i = 0; i < 2; ++i) {
        const int gr = br + wr + 16 * i + q * 4;
#pragma unroll
        for (int j = 0; j < 2; ++j) {
            const int gc = bc + wc + 16 * j + m16;
            if (gc < 1024) {
                const float b = bias[gc];
#pragma unroll
                for (int r = 0; r < 4; ++r)
                    C[(size_t)(gr + r) * 1024 + gc] = acc[i][j][r] + b;
            } else if (gc < 1039) {
                const float b = bias[gc];
#pragma unroll
                for (int r = 0; r < 4; ++r)
                    t[(size_t)(gr + r) * 15 + (gc - 1024)] = acc[i][j][r] + b;
            }
        }
    }
}

// ---------------------------------------------------------------------------
// Batch diversity (r11/r12 config): t (N,15 contiguous) -> dv_part.
// 2 i-rows/wave (no spill), flat 15-float LDS rows (0 conflicts),
// grid (512,4)=2048 blocks -> 8 blocks/CU.
// ---------------------------------------------------------------------------
#define DIV_TI 8
#define DIV_JC 4
__global__ __launch_bounds__(256)
void diversity_kernel(const float* __restrict__ t, float* __restrict__ dv_part, int N) {
    const int tid = threadIdx.x;
    const int lane = tid & 63;
    const int g = tid >> 6;
    const int i0 = blockIdx.x * DIV_TI + g * 2;
    const int jbeg = blockIdx.y * (N / DIV_JC);
    const int jend = jbeg + N / DIV_JC;

    float ti[2][15];
#pragma unroll
    for (int r = 0; r < 2; ++r)
#pragma unroll
        for (int d = 0; d < 15; ++d)
            ti[r][d] = t[(i0 + r) * 15 + d];

    float acc[2][5] = {};

    __shared__ float tj_s[256 * 15];
    for (int j0 = jbeg; j0 < jend; j0 += 256) {
        __syncthreads();
#pragma unroll
        for (int it = 0; it < 15; ++it)
            tj_s[it * 256 + tid] = t[j0 * 15 + it * 256 + tid];  // straight copy
        __syncthreads();
#pragma unroll
        for (int m = 0; m < 4; ++m) {
            const float* rp = tj_s + (m * 64 + lane) * 15;
#pragma unroll
            for (int r = 0; r < 2; ++r) {
#pragma unroll
                for (int k = 0; k < 5; ++k) {
                    const float s = fabsf(ti[r][3 * k]     - rp[3 * k])
                                  + fabsf(ti[r][3 * k + 1] - rp[3 * k + 1])
                                  + fabsf(ti[r][3 * k + 2] - rp[3 * k + 2]);
                    acc[r][k] += __expf(-s);
                }
            }
        }
    }

#pragma unroll
    for (int r = 0; r < 2; ++r)
#pragma unroll
        for (int k = 0; k < 5; ++k)
#pragma unroll
            for (int off = 32; off > 0; off >>= 1)
                acc[r][k] += __shfl_xor(acc[r][k], off, 64);

    if (lane == 0) {
        float* dst = dv_part + (size_t)blockIdx.y * N * 5;
#pragma unroll
        for (int r = 0; r < 2; ++r)
#pragma unroll
            for (int k = 0; k < 5; ++k)
                dst[(i0 + r) * 5 + k] = acc[r][k];
    }
}

// ---------------------------------------------------------------------------
// concat([h, sum(dv_part)]) -> LN(center) -> LeakyReLU -> bf16 (M x Cp)
// ---------------------------------------------------------------------------
__global__ void ln_lrelu_mid(const float* __restrict__ h,
                             const float* __restrict__ dv_part,
                             const float* __restrict__ beta,
                             unsigned short* __restrict__ out_bf,
                             int H, int D, int Cp, int M) {
    const int i = blockIdx.x;
    const int tid = threadIdx.x;
    const int C = H + D;
    float v[5];
    float s = 0.f, s2 = 0.f;
#pragma unroll
    for (int r = 0; r < 5; ++r) {
        const int c = tid + r * 256;
        if (c < C) {
            float x;
            if (c < H) {
                x = h[(size_t)i * H + c];
            } else {
                const int k = c - H;
                x = 0.f;
#pragma unroll
                for (int jc = 0; jc < DIV_JC; ++jc)
                    x += dv_part[(size_t)jc * M * D + i * D + k];
            }
            v[r] = x; s += x; s2 += x * x;
        }
    }
    __shared__ float rs[4], rs2[4];
    const int lane = tid & 63, wave = tid >> 6;
#pragma unroll
    for (int off = 32; off > 0; off >>= 1) {
        s += __shfl_down(s, off, 64);
        s2 += __shfl_down(s2, off, 64);
    }
    if (lane == 0) { rs[wave] = s; rs2[wave] = s2; }
    __syncthreads();
    const float S = rs[0] + rs[1] + rs[2] + rs[3];
    const float S2 = rs2[0] + rs2[1] + rs2[2] + rs2[3];
    const float mu = S / (float)C;
    const float var = S2 / (float)C - mu * mu;
    const float rstd = rsqrtf(var + LN_EPS);
#pragma unroll
    for (int r = 0; r < 5; ++r) {
        const int c = tid + r * 256;
        if (c < C) {
            float y = (v[r] - mu) * rstd + beta[c];
            y = (y >= 0.f) ? y : LRELU_ALPHA * y;
            out_bf[(size_t)i * Cp + c] = f2bf(y);
        } else if (c < Cp) {
            out_bf[(size_t)i * Cp + c] = 0;  // zero K-pad for next MFMA GEMM
        }
    }
}

// ---------------------------------------------------------------------------
// Final: concat -> LN -> LeakyReLU -> fused head dot: out[i] = y.wf + bf
// ---------------------------------------------------------------------------
__global__ void ln_lrelu_head(const float* __restrict__ h,
                              const float* __restrict__ dv_part,
                              const float* __restrict__ beta, const float* __restrict__ wf,
                              const float* __restrict__ bfp, float* __restrict__ out,
                              int H, int D, int M) {
    const int i = blockIdx.x;
    const int tid = threadIdx.x;
    const int C = H + D;
    float v[5];
    float s = 0.f, s2 = 0.f;
#pragma unroll
    for (int r = 0; r < 5; ++r) {
        const int c = tid + r * 256;
        if (c < C) {
            float x;
            if (c < H) {
                x = h[(size_t)i * H + c];
            } else {
                const int k = c - H;
                x = 0.f;
#pragma unroll
                for (int jc = 0; jc < DIV_JC; ++jc)
                    x += dv_part[(size_t)jc * M * D + i * D + k];
            }
            v[r] = x; s += x; s2 += x * x;
        }
    }
    __shared__ float rs[4], rs2[4], rh[4];
    const int lane = tid & 63, wave = tid >> 6;
#pragma unroll
    for (int off = 32; off > 0; off >>= 1) {
        s += __shfl_down(s, off, 64);
        s2 += __shfl_down(s2, off, 64);
    }
    if (lane == 0) { rs[wave] = s; rs2[wave] = s2; }
    __syncthreads();
    const float S = rs[0] + rs[1] + rs[2] + rs[3];
    const float S2 = rs2[0] + rs2[1] + rs2[2] + rs2[3];
    const float mu = S / (float)C;
    const float var = S2 / (float)C - mu * mu;
    const float rstd = rsqrtf(var + LN_EPS);
    float hsum = 0.f;
#pragma unroll
    for (int r = 0; r < 5; ++r) {
        const int c = tid + r * 256;
        if (c < C) {
            float y = (v[r] - mu) * rstd + beta[c];
            y = (y >= 0.f) ? y : LRELU_ALPHA * y;
            hsum += y * wf[c];
        }
    }
#pragma unroll
    for (int off = 32; off > 0; off >>= 1) hsum += __shfl_down(hsum, off, 64);
    if (lane == 0) rh[wave] = hsum;
    __syncthreads();
    if (tid == 0) out[i] = rh[0] + rh[1] + rh[2] + rh[3] + bfp[0];
}

extern "C" void kernel_launch(void* const* d_in, const int* in_sizes, int n_in,
                              void* d_out, int out_size, void* d_ws, size_t ws_size,
                              hipStream_t stream) {
    const float* x     = (const float*)d_in[0];
    const float* w0a   = (const float*)d_in[1];
    const float* b0a   = (const float*)d_in[2];
    const float* w0b   = (const float*)d_in[3];
    const float* b0b   = (const float*)d_in[4];
    const float* beta0 = (const float*)d_in[5];
    const float* w1a   = (const float*)d_in[6];
    const float* b1a   = (const float*)d_in[7];
    const float* w1b   = (const float*)d_in[8];
    const float* b1b   = (const float*)d_in[9];
    const float* beta1 = (const float*)d_in[10];
    const float* wf    = (const float*)d_in[11];
    const float* bf    = (const float*)d_in[12];
    float* out = (float*)d_out;

    const int M = 4096, NF = 512, HID = 1024, CP = 1056;

    // fp32 workspace (all offsets multiple-of-4 floats -> 16B aligned)
    float* h   = (float*)d_ws;                      // 4096 x 1024
    float* t   = h   + (size_t)M * HID;             // 4096 x 15 (contiguous)
    float* dvp = t   + (size_t)M * 15;              // DIV_JC x 4096 x 5
    float* be0 = dvp + (size_t)DIV_JC * M * 5;      // 1152
    float* be1 = be0 + NE;                          // 1152
    // bf16 workspace (16B-aligned)
    unsigned short* x_bf = (unsigned short*)(be1 + NE);              // 4096 x 512
    unsigned short* hc_bf = x_bf + (size_t)M * NF;                   // 4096 x 1056
    unsigned short* bT0   = hc_bf + (size_t)M * CP;                  // 1152 x 512
    unsigned short* bT1   = bT0 + (size_t)NE * NF;                   // 1152 x 1056

    // ---- fused prep ----
    prep_kernel<<<4011, 256, 0, stream>>>(x, w0a, b0a, w0b, b0b, w1a, b1a, w1b, b1b,
                                          x_bf, bT0, bT1, be0, be1);

    // ---- layer 0: GEMM writes h (cols<1024) and compact t (cols 1024..1038) ----
    mfma_gemm<<<dim3(NE / 64, M / 64), 256, 0, stream>>>(x_bf, NF, bT0, NF, be0, h, t, NF);
    diversity_kernel<<<dim3(M / DIV_TI, DIV_JC), 256, 0, stream>>>(t, dvp, M);
    ln_lrelu_mid<<<M, 256, 0, stream>>>(h, dvp, beta0, hc_bf, HID, 5, CP, M);

    // ---- layer 1 ----
    mfma_gemm<<<dim3(NE / 64, M / 64), 256, 0, stream>>>(hc_bf, CP, bT1, CP, be1, h, t, CP);
    diversity_kernel<<<dim3(M / DIV_TI, DIV_JC), 256, 0, stream>>>(t, dvp, M);
    ln_lrelu_head<<<M, 256, 0, stream>>>(h, dvp, beta1, wf, bf, out, HID, 5, M);
}